// Round 1
// baseline (423.126 us; speedup 1.0000x reference)
//
#include <hip/hip_runtime.h>
#include <cmath>

// Problem dims (fixed by reference setup_inputs)
#define BB 2
#define HH 480
#define WW 640
#define DD 256
#define HC 60
#define WC 80
#define NN (HC*WC)            // 4800

#define DET_BLOCKS 512
#define NTILES (NN/64)        // 75
#define DESC_BLOCKS (BB*NTILES*NTILES)  // 11250

// ws layout (float offsets)
#define OFF_DET0  0                       // 512*4
#define OFF_DET1  2048                    // 512*4
#define OFF_DESCP 4096                    // 11250
#define OFF_INVA  16384                   // BB*NN
#define OFF_INVB  (OFF_INVA + BB*NN)
#define OFF_WRW   (OFF_INVB + BB*NN)
#define OFF_WCL   (OFF_WRW + BB*NN)
#define OFF_VMC   (OFF_WCL + BB*NN)
#define OFF_WVMC  (OFF_VMC + BB*NN)

// ---------------- detector loss partial sums ----------------
__global__ __launch_bounds__(256) void det_kernel(
    const float* __restrict__ pred, const float* __restrict__ hmap,
    const float* __restrict__ vm, float* __restrict__ partials)
{
    float posl = 0.f, negl = 0.f, npos = 0.f, vsum = 0.f;
    const int total = BB*HH*WW;
    for (int i = blockIdx.x*256 + threadIdx.x; i < total; i += DET_BLOCKS*256) {
        float p = pred[i], h = hmap[i], v = vm[i];
        float omp = 1.f - p;
        if (h == 1.0f) {
            posl += logf(p + 1e-7f) * omp*omp * v;
            npos += 1.f;
        }
        if (h < 1.0f) {
            float oh = 1.f - h;
            float w4 = oh*oh; w4 *= w4;
            negl += logf(omp + 1e-7f) * p*p * w4 * v;
        }
        vsum += v;
    }
    __shared__ float red[256];
    int t = threadIdx.x;
    float vals[4] = {posl, negl, npos, vsum};
    for (int j = 0; j < 4; ++j) {
        red[t] = vals[j]; __syncthreads();
        for (int s = 128; s > 0; s >>= 1) { if (t < s) red[t] += red[t+s]; __syncthreads(); }
        if (t == 0) partials[blockIdx.x*4 + j] = red[0];
        __syncthreads();
    }
}

// ---------------- per-cell prep: inv norms, warped coords, resized masks ----
__device__ inline float bilin_cell(const float* __restrict__ x, int i, int j)
{
    float sr = (i + 0.5f) * ((float)HH/(float)HC) - 0.5f;
    sr = fminf(fmaxf(sr, 0.f), (float)(HH-1));
    int r0 = (int)floorf(sr); int r1 = min(r0+1, HH-1); float wr = sr - (float)r0;
    float sc = (j + 0.5f) * ((float)WW/(float)WC) - 0.5f;
    sc = fminf(fmaxf(sc, 0.f), (float)(WW-1));
    int c0 = (int)floorf(sc); int c1 = min(c0+1, WW-1); float wc = sc - (float)c0;
    float v00 = x[r0*WW+c0], v01 = x[r0*WW+c1];
    float v10 = x[r1*WW+c0], v11 = x[r1*WW+c1];
    float e0 = v00*(1.f-wr) + v10*wr;
    float e1 = v01*(1.f-wr) + v11*wr;
    return e0*(1.f-wc) + e1*wc;
}

__global__ __launch_bounds__(256) void prep_kernel(
    const float* __restrict__ desc, const float* __restrict__ wdesc,
    const float* __restrict__ vm, const float* __restrict__ wvm,
    const float* __restrict__ Hmat, float* __restrict__ ws)
{
    int idx = blockIdx.x*256 + threadIdx.x;
    if (idx >= BB*NN) return;
    int b = idx / NN, n = idx % NN;

    const float* a  = desc  + (size_t)b*DD*NN + n;
    const float* bp = wdesc + (size_t)b*DD*NN + n;
    float sa = 0.f, sb = 0.f;
    for (int d = 0; d < DD; ++d) {
        float x = a[(size_t)d*NN];  sa = fmaf(x, x, sa);
        float y = bp[(size_t)d*NN]; sb = fmaf(y, y, sb);
    }
    ws[OFF_INVA + idx] = 1.f / fmaxf(sqrtf(sa), 1e-12f);
    ws[OFF_INVB + idx] = 1.f / fmaxf(sqrtf(sb), 1e-12f);

    int i = n / WC, j = n % WC;
    float px = (float)(j*8 + 4), py = (float)(i*8 + 4);   // (col, row)
    const float* Hb = Hmat + b*9;  // Hmat shape (B,1,3,3)
    float w0 = Hb[0]*px + Hb[1]*py + Hb[2];
    float w1 = Hb[3]*px + Hb[4]*py + Hb[5];
    float w2 = Hb[6]*px + Hb[7]*py + Hb[8];
    ws[OFF_WRW + idx] = w1 / w2;   // warped row
    ws[OFF_WCL + idx] = w0 / w2;   // warped col

    ws[OFF_VMC  + idx] = (bilin_cell(vm  + (size_t)b*HH*WW, i, j) > 0.5f) ? 1.f : 0.f;
    ws[OFF_WVMC + idx] = (bilin_cell(wvm + (size_t)b*HH*WW, i, j) > 0.5f) ? 1.f : 0.f;
}

// ---------------- descriptor loss: fused GEMM + epilogue ----------------
__global__ __launch_bounds__(256) void desc_kernel(
    const float* __restrict__ desc, const float* __restrict__ wdesc,
    const float* __restrict__ ws, float* __restrict__ partials)
{
    const int b  = blockIdx.z;
    const int n0 = blockIdx.y * 64;
    const int m0 = blockIdx.x * 64;
    const float* A  = desc  + (size_t)b*DD*NN;
    const float* Bm = wdesc + (size_t)b*DD*NN;

    __shared__ float As[32][64];
    __shared__ float Bs[32][64];

    const int tid = threadIdx.x;
    const int tx = tid & 15, ty = tid >> 4;
    float acc[4][4] = {{0.f}};

    for (int k0 = 0; k0 < DD; k0 += 32) {
        #pragma unroll
        for (int l = 0; l < 8; ++l) {
            int e = tid + l*256;
            int kk = e >> 6, nn = e & 63;
            As[kk][nn] = A [(size_t)(k0+kk)*NN + n0 + nn];
            Bs[kk][nn] = Bm[(size_t)(k0+kk)*NN + m0 + nn];
        }
        __syncthreads();
        #pragma unroll
        for (int kk = 0; kk < 32; ++kk) {
            float4 av = *reinterpret_cast<const float4*>(&As[kk][ty*4]);
            float4 bv = *reinterpret_cast<const float4*>(&Bs[kk][tx*4]);
            float a4[4] = {av.x, av.y, av.z, av.w};
            float b4[4] = {bv.x, bv.y, bv.z, bv.w};
            #pragma unroll
            for (int r = 0; r < 4; ++r)
                #pragma unroll
                for (int c = 0; c < 4; ++c)
                    acc[r][c] = fmaf(a4[r], b4[c], acc[r][c]);
        }
        __syncthreads();
    }

    // epilogue: normalize dot, relu, margins, s-mask, validity, local sum
    const float* inva = ws + OFF_INVA + b*NN;
    const float* invb = ws + OFF_INVB + b*NN;
    const float* wrp  = ws + OFF_WRW + b*NN;
    const float* wcp  = ws + OFF_WCL + b*NN;
    const float* vmc  = ws + OFF_VMC + b*NN;
    const float* wvmc = ws + OFF_WVMC + b*NN;

    int nb = n0 + ty*4, mb = m0 + tx*4;
    float ia[4], wrv[4], wcv[4], va[4];
    #pragma unroll
    for (int r = 0; r < 4; ++r) {
        int n = nb + r;
        ia[r] = inva[n]; wrv[r] = wrp[n]; wcv[r] = wcp[n]; va[r] = vmc[n];
    }
    float ib[4], vb[4], crow[4], ccol[4];
    #pragma unroll
    for (int c = 0; c < 4; ++c) {
        int m = mb + c;
        ib[c] = invb[m]; vb[c] = wvmc[m];
        crow[c] = (float)((m / WC)*8 + 4);
        ccol[c] = (float)((m % WC)*8 + 4);
    }
    float sum = 0.f;
    #pragma unroll
    for (int r = 0; r < 4; ++r) {
        #pragma unroll
        for (int c = 0; c < 4; ++c) {
            float dot = fmaxf(acc[r][c] * ia[r] * ib[c], 0.f);
            float dr = crow[c] - wrv[r];
            float dc = ccol[c] - wcv[r];
            bool s = (dr*dr + dc*dc) <= 56.25f;   // (CELL-0.5)^2
            float term = s ? 250.f * fmaxf(1.f - dot, 0.f)
                           : fmaxf(dot - 0.2f, 0.f);
            sum += term * va[r] * vb[c];
        }
    }

    __shared__ float red[256];
    red[tid] = sum; __syncthreads();
    for (int s = 128; s > 0; s >>= 1) { if (tid < s) red[tid] += red[tid+s]; __syncthreads(); }
    if (tid == 0) {
        int bid = (blockIdx.z * gridDim.y + blockIdx.y) * gridDim.x + blockIdx.x;
        partials[bid] = red[0];
    }
}

// ---------------- finalize: deterministic reduction + outputs ----------------
__global__ __launch_bounds__(256) void finalize_kernel(
    const float* __restrict__ ws, float* __restrict__ out)
{
    __shared__ float red[256];
    int t = threadIdx.x;
    float res[2];
    float norm = 0.f;
    for (int pass = 0; pass < 2; ++pass) {
        const float* p = ws + (pass == 0 ? OFF_DET0 : OFF_DET1);
        float s0=0.f, s1=0.f, s2=0.f, s3=0.f;
        for (int i = t; i < DET_BLOCKS; i += 256) {
            s0 += p[i*4+0]; s1 += p[i*4+1]; s2 += p[i*4+2]; s3 += p[i*4+3];
        }
        float v[4] = {s0,s1,s2,s3};
        float tot[4];
        for (int j = 0; j < 4; ++j) {
            red[t] = v[j]; __syncthreads();
            for (int s = 128; s > 0; s >>= 1) { if (t < s) red[t] += red[t+s]; __syncthreads(); }
            tot[j] = red[0]; __syncthreads();
        }
        float posl = tot[0], negl = tot[1], npos = tot[2], vsum = tot[3];
        res[pass] = (npos == 0.f) ? -negl : -(posl + negl) / fmaxf(npos, 1.f);
        if (pass == 1) norm = vsum;   // normalization = wvm.sum()
    }
    float ds = 0.f;
    for (int i = t; i < DESC_BLOCKS; i += 256) ds += ws[OFF_DESCP + i];
    red[t] = ds; __syncthreads();
    for (int s = 128; s > 0; s >>= 1) { if (t < s) red[t] += red[t+s]; __syncthreads(); }
    float descsum = red[0];
    if (t == 0) {
        float desc_loss = descsum / norm;
        float total = res[0] + res[1] + 1e-4f * desc_loss;
        out[0] = total;
        out[1] = res[0];
        out[2] = res[1];
        out[3] = desc_loss;
    }
}

extern "C" void kernel_launch(void* const* d_in, const int* in_sizes, int n_in,
                              void* d_out, int out_size, void* d_ws, size_t ws_size,
                              hipStream_t stream)
{
    const float* prob  = (const float*)d_in[0];
    const float* htm   = (const float*)d_in[1];
    const float* vmask = (const float*)d_in[2];
    const float* wprob = (const float*)d_in[3];
    const float* wht   = (const float*)d_in[4];
    const float* wvm   = (const float*)d_in[5];
    const float* desc  = (const float*)d_in[6];
    const float* wdesc = (const float*)d_in[7];
    const float* Hm    = (const float*)d_in[8];
    float* ws  = (float*)d_ws;
    float* out = (float*)d_out;

    det_kernel<<<DET_BLOCKS, 256, 0, stream>>>(prob, htm, vmask, ws + OFF_DET0);
    det_kernel<<<DET_BLOCKS, 256, 0, stream>>>(wprob, wht, wvm, ws + OFF_DET1);
    prep_kernel<<<(BB*NN + 255)/256, 256, 0, stream>>>(desc, wdesc, vmask, wvm, Hm, ws);
    desc_kernel<<<dim3(NTILES, NTILES, BB), 256, 0, stream>>>(desc, wdesc, ws, ws + OFF_DESCP);
    finalize_kernel<<<1, 256, 0, stream>>>(ws, out);
}

// Round 2
// 193.028 us; speedup vs baseline: 2.1920x; 2.1920x over previous
//
#include <hip/hip_runtime.h>
#include <hip/hip_bf16.h>
#include <cmath>

// Problem dims (fixed by reference setup_inputs)
#define BB 2
#define HH 480
#define WW 640
#define DD 256
#define HC 60
#define WC 80
#define NN (HC*WC)            // 4800

#define DET_BLOCKS 512

// fp32 fallback tiling
#define NTILES64 (NN/64)                  // 75
#define DESC_BLOCKS_F32 (BB*NTILES64*NTILES64)  // 11250
// mfma tiling
#define TS 96
#define NTILES96 (NN/TS)                  // 50
#define DESC_BLOCKS_MFMA (BB*NTILES96*NTILES96) // 5000

// ws layout (float offsets)
#define OFF_DET0  0                       // 512*4
#define OFF_DET1  2048                    // 512*4
#define OFF_DESCP 4096                    // up to 11250
#define OFF_INVA  16384                   // BB*NN
#define OFF_INVB  (OFF_INVA + BB*NN)
#define OFF_WRW   (OFF_INVB + BB*NN)
#define OFF_WCL   (OFF_WRW + BB*NN)
#define OFF_VMC   (OFF_WCL + BB*NN)
#define OFF_WVMC  (OFF_VMC + BB*NN)
#define OFF_TA    81920                   // bf16 desc^T  [B][N][D]
#define TA_FLOATS (BB*NN*DD/2)            // 1228800 floats (bf16 storage)
#define OFF_TB    (OFF_TA + TA_FLOATS)
#define WS_NEED   ((size_t)(OFF_TB + TA_FLOATS) * 4)

typedef __attribute__((ext_vector_type(8))) short short8;
typedef __attribute__((ext_vector_type(4))) float f32x4;

// ---------------- detector loss partial sums ----------------
__global__ __launch_bounds__(256) void det_kernel(
    const float* __restrict__ pred, const float* __restrict__ hmap,
    const float* __restrict__ vm, float* __restrict__ partials)
{
    float posl = 0.f, negl = 0.f, npos = 0.f, vsum = 0.f;
    const int total = BB*HH*WW;
    for (int i = blockIdx.x*256 + threadIdx.x; i < total; i += DET_BLOCKS*256) {
        float p = pred[i], h = hmap[i], v = vm[i];
        float omp = 1.f - p;
        if (h == 1.0f) {
            posl += logf(p + 1e-7f) * omp*omp * v;
            npos += 1.f;
        }
        if (h < 1.0f) {
            float oh = 1.f - h;
            float w4 = oh*oh; w4 *= w4;
            negl += logf(omp + 1e-7f) * p*p * w4 * v;
        }
        vsum += v;
    }
    __shared__ float red[256];
    int t = threadIdx.x;
    float vals[4] = {posl, negl, npos, vsum};
    for (int j = 0; j < 4; ++j) {
        red[t] = vals[j]; __syncthreads();
        for (int s = 128; s > 0; s >>= 1) { if (t < s) red[t] += red[t+s]; __syncthreads(); }
        if (t == 0) partials[blockIdx.x*4 + j] = red[0];
        __syncthreads();
    }
}

// ---------------- per-cell prep: inv norms, warped coords, resized masks ----
__device__ inline float bilin_cell(const float* __restrict__ x, int i, int j)
{
    float sr = (i + 0.5f) * ((float)HH/(float)HC) - 0.5f;
    sr = fminf(fmaxf(sr, 0.f), (float)(HH-1));
    int r0 = (int)floorf(sr); int r1 = min(r0+1, HH-1); float wr = sr - (float)r0;
    float sc = (j + 0.5f) * ((float)WW/(float)WC) - 0.5f;
    sc = fminf(fmaxf(sc, 0.f), (float)(WW-1));
    int c0 = (int)floorf(sc); int c1 = min(c0+1, WW-1); float wc = sc - (float)c0;
    float v00 = x[r0*WW+c0], v01 = x[r0*WW+c1];
    float v10 = x[r1*WW+c0], v11 = x[r1*WW+c1];
    float e0 = v00*(1.f-wr) + v10*wr;
    float e1 = v01*(1.f-wr) + v11*wr;
    return e0*(1.f-wc) + e1*wc;
}

__global__ __launch_bounds__(256) void prep_kernel(
    const float* __restrict__ desc, const float* __restrict__ wdesc,
    const float* __restrict__ vm, const float* __restrict__ wvm,
    const float* __restrict__ Hmat, float* __restrict__ ws)
{
    int idx = blockIdx.x*256 + threadIdx.x;
    if (idx >= BB*NN) return;
    int b = idx / NN, n = idx % NN;

    const float* a  = desc  + (size_t)b*DD*NN + n;
    const float* bp = wdesc + (size_t)b*DD*NN + n;
    float sa = 0.f, sb = 0.f;
    for (int d = 0; d < DD; ++d) {
        float x = a[(size_t)d*NN];  sa = fmaf(x, x, sa);
        float y = bp[(size_t)d*NN]; sb = fmaf(y, y, sb);
    }
    ws[OFF_INVA + idx] = 1.f / fmaxf(sqrtf(sa), 1e-12f);
    ws[OFF_INVB + idx] = 1.f / fmaxf(sqrtf(sb), 1e-12f);

    int i = n / WC, j = n % WC;
    float px = (float)(j*8 + 4), py = (float)(i*8 + 4);   // (col, row)
    const float* Hb = Hmat + b*9;  // Hmat shape (B,1,3,3)
    float w0 = Hb[0]*px + Hb[1]*py + Hb[2];
    float w1 = Hb[3]*px + Hb[4]*py + Hb[5];
    float w2 = Hb[6]*px + Hb[7]*py + Hb[8];
    ws[OFF_WRW + idx] = w1 / w2;   // warped row
    ws[OFF_WCL + idx] = w0 / w2;   // warped col

    ws[OFF_VMC  + idx] = (bilin_cell(vm  + (size_t)b*HH*WW, i, j) > 0.5f) ? 1.f : 0.f;
    ws[OFF_WVMC + idx] = (bilin_cell(wvm + (size_t)b*HH*WW, i, j) > 0.5f) ? 1.f : 0.f;
}

// ---------------- transpose + bf16 cast: [b][d][n] f32 -> [b][n][d] bf16 ----
__global__ __launch_bounds__(256) void transpose_kernel(
    const float* __restrict__ desc, const float* __restrict__ wdesc,
    unsigned short* __restrict__ ta, unsigned short* __restrict__ tb)
{
    const int nb = blockIdx.x * 64;
    const int db = blockIdx.y * 64;
    const int z  = blockIdx.z;           // b*2 + which
    const int b  = z >> 1;
    const float* src = (z & 1) ? wdesc : desc;
    unsigned short* dst = (z & 1) ? tb : ta;
    src += (size_t)b*DD*NN;
    dst += (size_t)b*NN*DD;

    __shared__ float tile[64][65];
    const int tr = threadIdx.x >> 6;     // 0..3
    const int tc = threadIdx.x & 63;
    #pragma unroll
    for (int i = 0; i < 16; ++i) {
        int d = db + i*4 + tr;
        tile[i*4 + tr][tc] = src[(size_t)d*NN + nb + tc];
    }
    __syncthreads();
    #pragma unroll
    for (int i = 0; i < 16; ++i) {
        int nl = i*4 + tr;
        float v = tile[tc][nl];          // column read, stride 65 -> conflict-free
        __hip_bfloat16 h = __float2bfloat16(v);
        dst[(size_t)(nb + nl)*DD + db + tc] = __builtin_bit_cast(unsigned short, h);
    }
}

// ---------------- MFMA descriptor loss ----------------
// tile 96x96, K=256 fully LDS-resident, 4 waves (2x2), 3x3 frags of 16x16x32
__global__ __launch_bounds__(256) void desc_mfma(
    const unsigned short* __restrict__ ta, const unsigned short* __restrict__ tb,
    const float* __restrict__ ws, float* __restrict__ partials)
{
    const int b  = blockIdx.z;
    const int n0 = blockIdx.y * TS;
    const int m0 = blockIdx.x * TS;

    __shared__ unsigned short As[TS*DD];   // 48 KB, swizzled rows
    __shared__ unsigned short Bs[TS*DD];   // 48 KB

    const int tid  = threadIdx.x;
    const int lane = tid & 63;
    const int wid  = tid >> 6;             // 0..3
    const int wr   = wid >> 1, wc = wid & 1;

    const unsigned short* tab = ta + (size_t)b*NN*DD;
    const unsigned short* tbb = tb + (size_t)b*NN*DD;

    // ---- stage: global_load_lds width 16, pre-swizzled source ----
    // each wave stages 24 rows of A and 24 of B; 2 rows (1 KB) per issue
    {
        const int rlane = lane >> 5;       // 0/1: row within pair
        const int chunk = lane & 31;       // 16B chunk within 512B row
        #pragma unroll
        for (int i = 0; i < 12; ++i) {
            int rt = wid*24 + i*2 + rlane;             // row in tile
            int sc = chunk ^ (rt & 7);                 // swizzled source chunk
            const unsigned short* ga = tab + (size_t)(n0 + rt)*DD + sc*8;
            __builtin_amdgcn_global_load_lds(
                (const __attribute__((address_space(1))) void*)ga,
                (__attribute__((address_space(3))) void*)&As[(wid*24 + i*2)*DD],
                16, 0, 0);
            const unsigned short* gb = tbb + (size_t)(m0 + rt)*DD + sc*8;
            __builtin_amdgcn_global_load_lds(
                (const __attribute__((address_space(1))) void*)gb,
                (__attribute__((address_space(3))) void*)&Bs[(wid*24 + i*2)*DD],
                16, 0, 0);
        }
    }
    __syncthreads();

    // ---- K loop: 8 steps of K=32, 3x3 fragments per wave ----
    const int ln15 = lane & 15;
    const int kg   = lane >> 4;            // 0..3
    f32x4 acc[3][3] = {};
    #pragma unroll
    for (int ks = 0; ks < 8; ++ks) {
        short8 af[3], bf[3];
        #pragma unroll
        for (int f = 0; f < 3; ++f) {
            int ra = wr*48 + f*16 + ln15;
            int ca = (ks*4 + kg) ^ (ra & 7);           // swizzled 16B chunk
            af[f] = *(const short8*)((const char*)As + ra*512 + (ca << 4));
            int rb = wc*48 + f*16 + ln15;
            int cb = (ks*4 + kg) ^ (rb & 7);
            bf[f] = *(const short8*)((const char*)Bs + rb*512 + (cb << 4));
        }
        #pragma unroll
        for (int fi = 0; fi < 3; ++fi)
            #pragma unroll
            for (int fj = 0; fj < 3; ++fj)
                acc[fi][fj] = __builtin_amdgcn_mfma_f32_16x16x32_bf16(
                    af[fi], bf[fj], acc[fi][fj], 0, 0, 0);
    }

    // ---- epilogue ----
    const float* inva = ws + OFF_INVA + b*NN;
    const float* invb = ws + OFF_INVB + b*NN;
    const float* wrp  = ws + OFF_WRW + b*NN;
    const float* wcp  = ws + OFF_WCL + b*NN;
    const float* vmc  = ws + OFF_VMC + b*NN;
    const float* wvmc = ws + OFF_WVMC + b*NN;

    float ibv[3], vbv[3], crow[3], ccol[3];
    #pragma unroll
    for (int fj = 0; fj < 3; ++fj) {
        int m = m0 + wc*48 + fj*16 + ln15;
        ibv[fj] = invb[m]; vbv[fj] = wvmc[m];
        crow[fj] = (float)((m / WC)*8 + 4);
        ccol[fj] = (float)((m % WC)*8 + 4);
    }
    float sum = 0.f;
    #pragma unroll
    for (int fi = 0; fi < 3; ++fi) {
        #pragma unroll
        for (int reg = 0; reg < 4; ++reg) {
            int n = n0 + wr*48 + fi*16 + kg*4 + reg;
            float ia = inva[n], wrow = wrp[n], wcol = wcp[n], va = vmc[n];
            #pragma unroll
            for (int fj = 0; fj < 3; ++fj) {
                float dot = fmaxf(acc[fi][fj][reg] * ia * ibv[fj], 0.f);
                float dr = crow[fj] - wrow;
                float dc = ccol[fj] - wcol;
                bool s = (dr*dr + dc*dc) <= 56.25f;   // (CELL-0.5)^2
                float term = s ? 250.f * fmaxf(1.f - dot, 0.f)
                               : fmaxf(dot - 0.2f, 0.f);
                sum += term * va * vbv[fj];
            }
        }
    }

    __syncthreads();                        // all reads of As done
    float* red = (float*)As;                // reuse LDS
    red[tid] = sum; __syncthreads();
    for (int s = 128; s > 0; s >>= 1) { if (tid < s) red[tid] += red[tid+s]; __syncthreads(); }
    if (tid == 0) {
        int bid = (blockIdx.z * gridDim.y + blockIdx.y) * gridDim.x + blockIdx.x;
        partials[bid] = red[0];
    }
}

// ---------------- fp32 fallback descriptor loss (known-good) ----------------
__global__ __launch_bounds__(256) void desc_kernel(
    const float* __restrict__ desc, const float* __restrict__ wdesc,
    const float* __restrict__ ws, float* __restrict__ partials)
{
    const int b  = blockIdx.z;
    const int n0 = blockIdx.y * 64;
    const int m0 = blockIdx.x * 64;
    const float* A  = desc  + (size_t)b*DD*NN;
    const float* Bm = wdesc + (size_t)b*DD*NN;

    __shared__ float As[32][64];
    __shared__ float Bs[32][64];

    const int tid = threadIdx.x;
    const int tx = tid & 15, ty = tid >> 4;
    float acc[4][4] = {{0.f}};

    for (int k0 = 0; k0 < DD; k0 += 32) {
        #pragma unroll
        for (int l = 0; l < 8; ++l) {
            int e = tid + l*256;
            int kk = e >> 6, nn = e & 63;
            As[kk][nn] = A [(size_t)(k0+kk)*NN + n0 + nn];
            Bs[kk][nn] = Bm[(size_t)(k0+kk)*NN + m0 + nn];
        }
        __syncthreads();
        #pragma unroll
        for (int kk = 0; kk < 32; ++kk) {
            float4 av = *reinterpret_cast<const float4*>(&As[kk][ty*4]);
            float4 bv = *reinterpret_cast<const float4*>(&Bs[kk][tx*4]);
            float a4[4] = {av.x, av.y, av.z, av.w};
            float b4[4] = {bv.x, bv.y, bv.z, bv.w};
            #pragma unroll
            for (int r = 0; r < 4; ++r)
                #pragma unroll
                for (int c = 0; c < 4; ++c)
                    acc[r][c] = fmaf(a4[r], b4[c], acc[r][c]);
        }
        __syncthreads();
    }

    const float* inva = ws + OFF_INVA + b*NN;
    const float* invb = ws + OFF_INVB + b*NN;
    const float* wrp  = ws + OFF_WRW + b*NN;
    const float* wcp  = ws + OFF_WCL + b*NN;
    const float* vmc  = ws + OFF_VMC + b*NN;
    const float* wvmc = ws + OFF_WVMC + b*NN;

    int nb = n0 + ty*4, mb = m0 + tx*4;
    float ia[4], wrv[4], wcv[4], va[4];
    #pragma unroll
    for (int r = 0; r < 4; ++r) {
        int n = nb + r;
        ia[r] = inva[n]; wrv[r] = wrp[n]; wcv[r] = wcp[n]; va[r] = vmc[n];
    }
    float ib[4], vb[4], crow[4], ccol[4];
    #pragma unroll
    for (int c = 0; c < 4; ++c) {
        int m = mb + c;
        ib[c] = invb[m]; vb[c] = wvmc[m];
        crow[c] = (float)((m / WC)*8 + 4);
        ccol[c] = (float)((m % WC)*8 + 4);
    }
    float sum = 0.f;
    #pragma unroll
    for (int r = 0; r < 4; ++r) {
        #pragma unroll
        for (int c = 0; c < 4; ++c) {
            float dot = fmaxf(acc[r][c] * ia[r] * ib[c], 0.f);
            float dr = crow[c] - wrv[r];
            float dc = ccol[c] - wcv[r];
            bool s = (dr*dr + dc*dc) <= 56.25f;
            float term = s ? 250.f * fmaxf(1.f - dot, 0.f)
                           : fmaxf(dot - 0.2f, 0.f);
            sum += term * va[r] * vb[c];
        }
    }

    __shared__ float red[256];
    red[tid] = sum; __syncthreads();
    for (int s = 128; s > 0; s >>= 1) { if (tid < s) red[tid] += red[tid+s]; __syncthreads(); }
    if (tid == 0) {
        int bid = (blockIdx.z * gridDim.y + blockIdx.y) * gridDim.x + blockIdx.x;
        partials[bid] = red[0];
    }
}

// ---------------- finalize: deterministic reduction + outputs ----------------
__global__ __launch_bounds__(256) void finalize_kernel(
    const float* __restrict__ ws, float* __restrict__ out, int desc_nblocks)
{
    __shared__ float red[256];
    int t = threadIdx.x;
    float res[2];
    float norm = 0.f;
    for (int pass = 0; pass < 2; ++pass) {
        const float* p = ws + (pass == 0 ? OFF_DET0 : OFF_DET1);
        float s0=0.f, s1=0.f, s2=0.f, s3=0.f;
        for (int i = t; i < DET_BLOCKS; i += 256) {
            s0 += p[i*4+0]; s1 += p[i*4+1]; s2 += p[i*4+2]; s3 += p[i*4+3];
        }
        float v[4] = {s0,s1,s2,s3};
        float tot[4];
        for (int j = 0; j < 4; ++j) {
            red[t] = v[j]; __syncthreads();
            for (int s = 128; s > 0; s >>= 1) { if (t < s) red[t] += red[t+s]; __syncthreads(); }
            tot[j] = red[0]; __syncthreads();
        }
        float posl = tot[0], negl = tot[1], npos = tot[2], vsum = tot[3];
        res[pass] = (npos == 0.f) ? -negl : -(posl + negl) / fmaxf(npos, 1.f);
        if (pass == 1) norm = vsum;   // normalization = wvm.sum()
    }
    float ds = 0.f;
    for (int i = t; i < desc_nblocks; i += 256) ds += ws[OFF_DESCP + i];
    red[t] = ds; __syncthreads();
    for (int s = 128; s > 0; s >>= 1) { if (t < s) red[t] += red[t+s]; __syncthreads(); }
    float descsum = red[0];
    if (t == 0) {
        float desc_loss = descsum / norm;
        float total = res[0] + res[1] + 1e-4f * desc_loss;
        out[0] = total;
        out[1] = res[0];
        out[2] = res[1];
        out[3] = desc_loss;
    }
}

extern "C" void kernel_launch(void* const* d_in, const int* in_sizes, int n_in,
                              void* d_out, int out_size, void* d_ws, size_t ws_size,
                              hipStream_t stream)
{
    const float* prob  = (const float*)d_in[0];
    const float* htm   = (const float*)d_in[1];
    const float* vmask = (const float*)d_in[2];
    const float* wprob = (const float*)d_in[3];
    const float* wht   = (const float*)d_in[4];
    const float* wvm   = (const float*)d_in[5];
    const float* desc  = (const float*)d_in[6];
    const float* wdesc = (const float*)d_in[7];
    const float* Hm    = (const float*)d_in[8];
    float* ws  = (float*)d_ws;
    float* out = (float*)d_out;

    det_kernel<<<DET_BLOCKS, 256, 0, stream>>>(prob, htm, vmask, ws + OFF_DET0);
    det_kernel<<<DET_BLOCKS, 256, 0, stream>>>(wprob, wht, wvm, ws + OFF_DET1);
    prep_kernel<<<(BB*NN + 255)/256, 256, 0, stream>>>(desc, wdesc, vmask, wvm, Hm, ws);

    if (ws_size >= WS_NEED) {
        unsigned short* ta = (unsigned short*)(ws + OFF_TA);
        unsigned short* tb = (unsigned short*)(ws + OFF_TB);
        transpose_kernel<<<dim3(NN/64, DD/64, BB*2), 256, 0, stream>>>(desc, wdesc, ta, tb);
        desc_mfma<<<dim3(NTILES96, NTILES96, BB), 256, 0, stream>>>(ta, tb, ws, ws + OFF_DESCP);
        finalize_kernel<<<1, 256, 0, stream>>>(ws, out, DESC_BLOCKS_MFMA);
    } else {
        desc_kernel<<<dim3(NTILES64, NTILES64, BB), 256, 0, stream>>>(desc, wdesc, ws, ws + OFF_DESCP);
        finalize_kernel<<<1, 256, 0, stream>>>(ws, out, DESC_BLOCKS_F32);
    }
}

// Round 3
// 158.873 us; speedup vs baseline: 2.6633x; 1.2150x over previous
//
#include <hip/hip_runtime.h>
#include <hip/hip_bf16.h>
#include <cmath>

// Problem dims (fixed by reference setup_inputs)
#define BB 2
#define HH 480
#define WW 640
#define DD 256
#define HC 60
#define WC 80
#define NN (HC*WC)            // 4800

#define DET_BLOCKS 300

// fp32 fallback tiling
#define NTILES64 (NN/64)                  // 75
#define DESC_BLOCKS_F32 (BB*NTILES64*NTILES64)  // 11250
// mfma tiling: 192x192 block, 4 waves of 96x96 (6x6 frags of 16x16x32)
#define TS2 192
#define BK 32
#define NT192 (NN/TS2)                    // 25
#define DESC_BLOCKS_MFMA (BB*NT192*NT192) // 1250

// ws layout (float offsets)
#define OFF_DET0  0                       // 300*4
#define OFF_DET1  2048                    // 300*4
#define OFF_DESCP 4096                    // up to 11250
#define OFF_INVA  16384                   // BB*NN
#define OFF_INVB  (OFF_INVA + BB*NN)
#define OFF_WRW   (OFF_INVB + BB*NN)
#define OFF_WCL   (OFF_WRW + BB*NN)
#define OFF_VMC   (OFF_WCL + BB*NN)
#define OFF_WVMC  (OFF_VMC + BB*NN)
#define OFF_TA    81920                   // bf16 desc^T  [B][N][D]
#define TA_FLOATS (BB*NN*DD/2)            // 1228800 floats (bf16 storage)
#define OFF_TB    (OFF_TA + TA_FLOATS)
#define WS_NEED   ((size_t)(OFF_TB + TA_FLOATS) * 4)

typedef __attribute__((ext_vector_type(8))) short short8;
typedef __attribute__((ext_vector_type(4))) float f32x4;

// ---------------- detector loss partial sums (both sets, float4) ----------
__device__ inline void det_accum(float p, float h, float v,
                                 float& posl, float& negl, float& npos, float& vsum)
{
    float omp = 1.f - p;
    if (h == 1.0f) {
        posl += logf(p + 1e-7f) * omp*omp * v;
        npos += 1.f;
    }
    if (h < 1.0f) {
        float oh = 1.f - h;
        float w4 = oh*oh; w4 *= w4;
        negl += logf(omp + 1e-7f) * p*p * w4 * v;
    }
    vsum += v;
}

__global__ __launch_bounds__(256) void det_kernel(
    const float* __restrict__ pred0, const float* __restrict__ hmap0, const float* __restrict__ vm0,
    const float* __restrict__ pred1, const float* __restrict__ hmap1, const float* __restrict__ vm1,
    float* __restrict__ ws)
{
    const int set = blockIdx.y;
    const float4* pred = (const float4*)(set ? pred1 : pred0);
    const float4* hmap = (const float4*)(set ? hmap1 : hmap0);
    const float4* vm   = (const float4*)(set ? vm1   : vm0);
    float* partials = ws + (set ? OFF_DET1 : OFF_DET0);

    float posl = 0.f, negl = 0.f, npos = 0.f, vsum = 0.f;
    const int total4 = BB*HH*WW/4;        // 307200
    for (int i = blockIdx.x*256 + threadIdx.x; i < total4; i += DET_BLOCKS*256) {
        float4 p = pred[i], h = hmap[i], v = vm[i];
        det_accum(p.x, h.x, v.x, posl, negl, npos, vsum);
        det_accum(p.y, h.y, v.y, posl, negl, npos, vsum);
        det_accum(p.z, h.z, v.z, posl, negl, npos, vsum);
        det_accum(p.w, h.w, v.w, posl, negl, npos, vsum);
    }
    __shared__ float red[256];
    int t = threadIdx.x;
    float vals[4] = {posl, negl, npos, vsum};
    for (int j = 0; j < 4; ++j) {
        red[t] = vals[j]; __syncthreads();
        for (int s = 128; s > 0; s >>= 1) { if (t < s) red[t] += red[t+s]; __syncthreads(); }
        if (t == 0) partials[blockIdx.x*4 + j] = red[0];
        __syncthreads();
    }
}

// ---------------- per-cell prep: inv norms, warped coords, resized masks ----
__device__ inline float bilin_cell(const float* __restrict__ x, int i, int j)
{
    float sr = (i + 0.5f) * ((float)HH/(float)HC) - 0.5f;
    sr = fminf(fmaxf(sr, 0.f), (float)(HH-1));
    int r0 = (int)floorf(sr); int r1 = min(r0+1, HH-1); float wr = sr - (float)r0;
    float sc = (j + 0.5f) * ((float)WW/(float)WC) - 0.5f;
    sc = fminf(fmaxf(sc, 0.f), (float)(WW-1));
    int c0 = (int)floorf(sc); int c1 = min(c0+1, WW-1); float wc = sc - (float)c0;
    float v00 = x[r0*WW+c0], v01 = x[r0*WW+c1];
    float v10 = x[r1*WW+c0], v11 = x[r1*WW+c1];
    float e0 = v00*(1.f-wr) + v10*wr;
    float e1 = v01*(1.f-wr) + v11*wr;
    return e0*(1.f-wc) + e1*wc;
}

__global__ __launch_bounds__(256) void prep_kernel(
    const float* __restrict__ desc, const float* __restrict__ wdesc,
    const float* __restrict__ vm, const float* __restrict__ wvm,
    const float* __restrict__ Hmat, float* __restrict__ ws)
{
    int idx = blockIdx.x*256 + threadIdx.x;
    if (idx >= BB*NN) return;
    int b = idx / NN, n = idx % NN;

    const float* a  = desc  + (size_t)b*DD*NN + n;
    const float* bp = wdesc + (size_t)b*DD*NN + n;
    float sa = 0.f, sb = 0.f;
    for (int d = 0; d < DD; ++d) {
        float x = a[(size_t)d*NN];  sa = fmaf(x, x, sa);
        float y = bp[(size_t)d*NN]; sb = fmaf(y, y, sb);
    }
    ws[OFF_INVA + idx] = 1.f / fmaxf(sqrtf(sa), 1e-12f);
    ws[OFF_INVB + idx] = 1.f / fmaxf(sqrtf(sb), 1e-12f);

    int i = n / WC, j = n % WC;
    float px = (float)(j*8 + 4), py = (float)(i*8 + 4);   // (col, row)
    const float* Hb = Hmat + b*9;  // Hmat shape (B,1,3,3)
    float w0 = Hb[0]*px + Hb[1]*py + Hb[2];
    float w1 = Hb[3]*px + Hb[4]*py + Hb[5];
    float w2 = Hb[6]*px + Hb[7]*py + Hb[8];
    ws[OFF_WRW + idx] = w1 / w2;   // warped row
    ws[OFF_WCL + idx] = w0 / w2;   // warped col

    ws[OFF_VMC  + idx] = (bilin_cell(vm  + (size_t)b*HH*WW, i, j) > 0.5f) ? 1.f : 0.f;
    ws[OFF_WVMC + idx] = (bilin_cell(wvm + (size_t)b*HH*WW, i, j) > 0.5f) ? 1.f : 0.f;
}

// ---------------- transpose + bf16 cast: [b][d][n] f32 -> [b][n][d] bf16 ----
__global__ __launch_bounds__(256) void transpose_kernel(
    const float* __restrict__ desc, const float* __restrict__ wdesc,
    unsigned short* __restrict__ ta, unsigned short* __restrict__ tb)
{
    const int nb = blockIdx.x * 64;
    const int db = blockIdx.y * 64;
    const int z  = blockIdx.z;           // b*2 + which
    const int b  = z >> 1;
    const float* src = (z & 1) ? wdesc : desc;
    unsigned short* dst = (z & 1) ? tb : ta;
    src += (size_t)b*DD*NN;
    dst += (size_t)b*NN*DD;

    __shared__ float tile[64][65];
    const int tr = threadIdx.x >> 6;     // 0..3
    const int tc = threadIdx.x & 63;
    #pragma unroll
    for (int i = 0; i < 16; ++i) {
        int d = db + i*4 + tr;
        tile[i*4 + tr][tc] = src[(size_t)d*NN + nb + tc];
    }
    __syncthreads();
    #pragma unroll
    for (int i = 0; i < 16; ++i) {
        int nl = i*4 + tr;
        float v = tile[tc][nl];          // column read, stride 65 -> conflict-free
        __hip_bfloat16 h = __float2bfloat16(v);
        dst[(size_t)(nb + nl)*DD + db + tc] = __builtin_bit_cast(unsigned short, h);
    }
}

// ---------------- MFMA descriptor loss v2 ----------------
// block 192x192, 4 waves (2x2) of 96x96 (6x6 frags 16x16x32), BK=32 dbuf
__global__ __launch_bounds__(256) void desc_mfma(
    const unsigned short* __restrict__ ta, const unsigned short* __restrict__ tb,
    const float* __restrict__ ws, float* __restrict__ partials)
{
    const int b  = blockIdx.z;
    const int n0 = blockIdx.y * TS2;
    const int m0 = blockIdx.x * TS2;

    __shared__ unsigned short As[2][TS2*BK];   // 12 KB per buffer
    __shared__ unsigned short Bs[2][TS2*BK];   // total 48 KB

    const int tid  = threadIdx.x;
    const int lane = tid & 63;
    const int wid  = tid >> 6;             // 0..3
    const int wr   = wid >> 1, wc = wid & 1;

    const unsigned short* tab = ta + (size_t)b*NN*DD;
    const unsigned short* tbb = tb + (size_t)b*NN*DD;

    // stage one BK=32 chunk of A and B tiles into buffer `buf`.
    // dest linear: chunk of 16 rows x 64B = 1024B; lane l writes row l>>2, slot l&3
    const int srow = lane >> 2;            // 0..15
    const int sslot = lane & 3;            // 16B slot (8 ushort)
#define STAGE(t_, buf_)                                                          \
    {                                                                            \
        const int k0 = (t_)*BK;                                                  \
        _Pragma("unroll")                                                        \
        for (int c = 0; c < 3; ++c) {                                            \
            int chunk = wid*3 + c;                                               \
            int row = chunk*16 + srow;                                           \
            __builtin_amdgcn_global_load_lds(                                    \
                (const __attribute__((address_space(1))) void*)                  \
                    (tab + (size_t)(n0+row)*DD + k0 + sslot*8),                  \
                (__attribute__((address_space(3))) void*)&As[buf_][chunk*16*BK], \
                16, 0, 0);                                                       \
            __builtin_amdgcn_global_load_lds(                                    \
                (const __attribute__((address_space(1))) void*)                  \
                    (tbb + (size_t)(m0+row)*DD + k0 + sslot*8),                  \
                (__attribute__((address_space(3))) void*)&Bs[buf_][chunk*16*BK], \
                16, 0, 0);                                                       \
        }                                                                        \
    }

    const int ln15   = lane & 15;
    const int slot16 = lane >> 4;          // 0..3: k-slot within BK=32 row
    f32x4 acc[6][6] = {};

    STAGE(0, 0);
    __syncthreads();

    #pragma unroll
    for (int t = 0; t < 8; ++t) {
        if (t < 7) STAGE(t+1, (t+1)&1);
        const unsigned short* Ab = As[t&1];
        const unsigned short* Bb = Bs[t&1];
        short8 af[6], bf[6];
        // rows stride 64B (half bank period): 16 rows x 4 slots covers all
        // 8 bank-groups uniformly -> conflict-free, no swizzle needed.
        #pragma unroll
        for (int f = 0; f < 6; ++f) {
            int ra = wr*96 + f*16 + ln15;
            af[f] = *(const short8*)((const char*)Ab + ra*64 + slot16*16);
            int rb = wc*96 + f*16 + ln15;
            bf[f] = *(const short8*)((const char*)Bb + rb*64 + slot16*16);
        }
        #pragma unroll
        for (int fi = 0; fi < 6; ++fi)
            #pragma unroll
            for (int fj = 0; fj < 6; ++fj)
                acc[fi][fj] = __builtin_amdgcn_mfma_f32_16x16x32_bf16(
                    af[fi], bf[fj], acc[fi][fj], 0, 0, 0);
        __syncthreads();
    }

    // ---- epilogue ----
    const float* inva = ws + OFF_INVA + b*NN;
    const float* invb = ws + OFF_INVB + b*NN;
    const float* wrp  = ws + OFF_WRW + b*NN;
    const float* wcp  = ws + OFF_WCL + b*NN;
    const float* vmc  = ws + OFF_VMC + b*NN;
    const float* wvmc = ws + OFF_WVMC + b*NN;

    float ibv[6], vbv[6], crow[6], ccol[6];
    #pragma unroll
    for (int fj = 0; fj < 6; ++fj) {
        int m = m0 + wc*96 + fj*16 + ln15;
        ibv[fj] = invb[m]; vbv[fj] = wvmc[m];
        crow[fj] = (float)((m / WC)*8 + 4);
        ccol[fj] = (float)((m % WC)*8 + 4);
    }
    float sum = 0.f;
    #pragma unroll
    for (int fi = 0; fi < 6; ++fi) {
        #pragma unroll
        for (int reg = 0; reg < 4; ++reg) {
            int n = n0 + wr*96 + fi*16 + slot16*4 + reg;
            float ia = inva[n], wrow = wrp[n], wcol = wcp[n], va = vmc[n];
            #pragma unroll
            for (int fj = 0; fj < 6; ++fj) {
                float dot = fmaxf(acc[fi][fj][reg] * ia * ibv[fj], 0.f);
                float dr = crow[fj] - wrow;
                float dc = ccol[fj] - wcol;
                bool s = (dr*dr + dc*dc) <= 56.25f;   // (CELL-0.5)^2
                float term = s ? 250.f * fmaxf(1.f - dot, 0.f)
                               : fmaxf(dot - 0.2f, 0.f);
                sum += term * va * vbv[fj];
            }
        }
    }

    __syncthreads();                        // all LDS reads done
    float* red = (float*)&As[0][0];         // reuse LDS
    red[tid] = sum; __syncthreads();
    for (int s = 128; s > 0; s >>= 1) { if (tid < s) red[tid] += red[tid+s]; __syncthreads(); }
    if (tid == 0) {
        int bid = (blockIdx.z * gridDim.y + blockIdx.y) * gridDim.x + blockIdx.x;
        partials[bid] = red[0];
    }
#undef STAGE
}

// ---------------- fp32 fallback descriptor loss (known-good) ----------------
__global__ __launch_bounds__(256) void desc_kernel(
    const float* __restrict__ desc, const float* __restrict__ wdesc,
    const float* __restrict__ ws, float* __restrict__ partials)
{
    const int b  = blockIdx.z;
    const int n0 = blockIdx.y * 64;
    const int m0 = blockIdx.x * 64;
    const float* A  = desc  + (size_t)b*DD*NN;
    const float* Bm = wdesc + (size_t)b*DD*NN;

    __shared__ float As[32][64];
    __shared__ float Bs[32][64];

    const int tid = threadIdx.x;
    const int tx = tid & 15, ty = tid >> 4;
    float acc[4][4] = {{0.f}};

    for (int k0 = 0; k0 < DD; k0 += 32) {
        #pragma unroll
        for (int l = 0; l < 8; ++l) {
            int e = tid + l*256;
            int kk = e >> 6, nn = e & 63;
            As[kk][nn] = A [(size_t)(k0+kk)*NN + n0 + nn];
            Bs[kk][nn] = Bm[(size_t)(k0+kk)*NN + m0 + nn];
        }
        __syncthreads();
        #pragma unroll
        for (int kk = 0; kk < 32; ++kk) {
            float4 av = *reinterpret_cast<const float4*>(&As[kk][ty*4]);
            float4 bv = *reinterpret_cast<const float4*>(&Bs[kk][tx*4]);
            float a4[4] = {av.x, av.y, av.z, av.w};
            float b4[4] = {bv.x, bv.y, bv.z, bv.w};
            #pragma unroll
            for (int r = 0; r < 4; ++r)
                #pragma unroll
                for (int c = 0; c < 4; ++c)
                    acc[r][c] = fmaf(a4[r], b4[c], acc[r][c]);
        }
        __syncthreads();
    }

    const float* inva = ws + OFF_INVA + b*NN;
    const float* invb = ws + OFF_INVB + b*NN;
    const float* wrp  = ws + OFF_WRW + b*NN;
    const float* wcp  = ws + OFF_WCL + b*NN;
    const float* vmc  = ws + OFF_VMC + b*NN;
    const float* wvmc = ws + OFF_WVMC + b*NN;

    int nb = n0 + ty*4, mb = m0 + tx*4;
    float ia[4], wrv[4], wcv[4], va[4];
    #pragma unroll
    for (int r = 0; r < 4; ++r) {
        int n = nb + r;
        ia[r] = inva[n]; wrv[r] = wrp[n]; wcv[r] = wcp[n]; va[r] = vmc[n];
    }
    float ib[4], vb[4], crow[4], ccol[4];
    #pragma unroll
    for (int c = 0; c < 4; ++c) {
        int m = mb + c;
        ib[c] = invb[m]; vb[c] = wvmc[m];
        crow[c] = (float)((m / WC)*8 + 4);
        ccol[c] = (float)((m % WC)*8 + 4);
    }
    float sum = 0.f;
    #pragma unroll
    for (int r = 0; r < 4; ++r) {
        #pragma unroll
        for (int c = 0; c < 4; ++c) {
            float dot = fmaxf(acc[r][c] * ia[r] * ib[c], 0.f);
            float dr = crow[c] - wrv[r];
            float dc = ccol[c] - wcv[r];
            bool s = (dr*dr + dc*dc) <= 56.25f;
            float term = s ? 250.f * fmaxf(1.f - dot, 0.f)
                           : fmaxf(dot - 0.2f, 0.f);
            sum += term * va[r] * vb[c];
        }
    }

    __shared__ float red[256];
    red[tid] = sum; __syncthreads();
    for (int s = 128; s > 0; s >>= 1) { if (tid < s) red[tid] += red[tid+s]; __syncthreads(); }
    if (tid == 0) {
        int bid = (blockIdx.z * gridDim.y + blockIdx.y) * gridDim.x + blockIdx.x;
        partials[bid] = red[0];
    }
}

// ---------------- finalize: deterministic reduction + outputs ----------------
__global__ __launch_bounds__(256) void finalize_kernel(
    const float* __restrict__ ws, float* __restrict__ out, int desc_nblocks)
{
    __shared__ float red[256];
    int t = threadIdx.x;
    float res[2];
    float norm = 0.f;
    for (int pass = 0; pass < 2; ++pass) {
        const float* p = ws + (pass == 0 ? OFF_DET0 : OFF_DET1);
        float s0=0.f, s1=0.f, s2=0.f, s3=0.f;
        for (int i = t; i < DET_BLOCKS; i += 256) {
            s0 += p[i*4+0]; s1 += p[i*4+1]; s2 += p[i*4+2]; s3 += p[i*4+3];
        }
        float v[4] = {s0,s1,s2,s3};
        float tot[4];
        for (int j = 0; j < 4; ++j) {
            red[t] = v[j]; __syncthreads();
            for (int s = 128; s > 0; s >>= 1) { if (t < s) red[t] += red[t+s]; __syncthreads(); }
            tot[j] = red[0]; __syncthreads();
        }
        float posl = tot[0], negl = tot[1], npos = tot[2], vsum = tot[3];
        res[pass] = (npos == 0.f) ? -negl : -(posl + negl) / fmaxf(npos, 1.f);
        if (pass == 1) norm = vsum;   // normalization = wvm.sum()
    }
    float ds = 0.f;
    for (int i = t; i < desc_nblocks; i += 256) ds += ws[OFF_DESCP + i];
    red[t] = ds; __syncthreads();
    for (int s = 128; s > 0; s >>= 1) { if (t < s) red[t] += red[t+s]; __syncthreads(); }
    float descsum = red[0];
    if (t == 0) {
        float desc_loss = descsum / norm;
        float total = res[0] + res[1] + 1e-4f * desc_loss;
        out[0] = total;
        out[1] = res[0];
        out[2] = res[1];
        out[3] = desc_loss;
    }
}

extern "C" void kernel_launch(void* const* d_in, const int* in_sizes, int n_in,
                              void* d_out, int out_size, void* d_ws, size_t ws_size,
                              hipStream_t stream)
{
    const float* prob  = (const float*)d_in[0];
    const float* htm   = (const float*)d_in[1];
    const float* vmask = (const float*)d_in[2];
    const float* wprob = (const float*)d_in[3];
    const float* wht   = (const float*)d_in[4];
    const float* wvm   = (const float*)d_in[5];
    const float* desc  = (const float*)d_in[6];
    const float* wdesc = (const float*)d_in[7];
    const float* Hm    = (const float*)d_in[8];
    float* ws  = (float*)d_ws;
    float* out = (float*)d_out;

    det_kernel<<<dim3(DET_BLOCKS, 2), 256, 0, stream>>>(
        prob, htm, vmask, wprob, wht, wvm, ws);
    prep_kernel<<<(BB*NN + 255)/256, 256, 0, stream>>>(desc, wdesc, vmask, wvm, Hm, ws);

    if (ws_size >= WS_NEED) {
        unsigned short* ta = (unsigned short*)(ws + OFF_TA);
        unsigned short* tb = (unsigned short*)(ws + OFF_TB);
        transpose_kernel<<<dim3(NN/64, DD/64, BB*2), 256, 0, stream>>>(desc, wdesc, ta, tb);
        desc_mfma<<<dim3(NT192, NT192, BB), 256, 0, stream>>>(ta, tb, ws, ws + OFF_DESCP);
        finalize_kernel<<<1, 256, 0, stream>>>(ws, out, DESC_BLOCKS_MFMA);
    } else {
        desc_kernel<<<dim3(NTILES64, NTILES64, BB), 256, 0, stream>>>(desc, wdesc, ws, ws + OFF_DESCP);
        finalize_kernel<<<1, 256, 0, stream>>>(ws, out, DESC_BLOCKS_F32);
    }
}